// Round 2
// baseline (3596.741 us; speedup 1.0000x reference)
//
#include <hip/hip_runtime.h>
#include <climits>

// Problem constants (fixed by the reference): B=8192 rows, D=512 features.
#define NB 8192
#define ND 512

// Zero the scalar output (harness poisons d_out before every timed launch).
__global__ __launch_bounds__(256) void zero_k(float* out, int n) {
    int g = blockIdx.x * 256 + threadIdx.x;
    if (g < n) out[g] = 0.0f;
}

// Fused semi-hard mining + loss for one pass z per blockIdx.y:
//   z=0: anchors=img rows, scan=txt   (sim rows),    margin
//   z=1: anchors=txt rows, scan=img   (sim.T rows),  margin
//   z=2: anchors=img rows, scan=cr    (sim_cr rows), margin_cr
//   z=3: anchors=cr  rows, scan=img   (sim_cr.T),    margin_cr
// Each block owns 64 anchors; scans 64-column chunks of the (virtual) sim
// matrix with early exit once every anchor has found its FIRST valid
// negative (argmax of bool == first true). Contribution per resolved row is
// lm = sim_an - diag + margin (guaranteed in (0, margin) by the predicate,
// so relu is a no-op). No workspace used at all.
__global__ __launch_bounds__(256) void mine_k(const float* __restrict__ img,
                                              const float* __restrict__ txt,
                                              const float* __restrict__ cr,
                                              const int*   __restrict__ labels,
                                              const int*   __restrict__ flagp,
                                              const float* __restrict__ margin,
                                              const float* __restrict__ betap,
                                              float* __restrict__ out) {
    __shared__ __align__(16) float As[16][64];
    __shared__ __align__(16) float Bs[16][64];
    __shared__ float aRn[64], aDg[64], aMg[64];
    __shared__ int   aLab[64];
    __shared__ float colRn[64];
    __shared__ int   colLab[64];
    __shared__ int   resIdx[64], prevIdx[64];
    __shared__ int   cnt;
    __shared__ float blockAcc;

    const int tid  = threadIdx.x;
    const int z    = blockIdx.y;
    const int a0   = blockIdx.x * 64;
    const int flag = flagp[0];

    const float* A = (z == 1) ? txt : (z == 3) ? cr : img;
    const float* B = (z == 0) ? txt : (z == 2) ? cr : img;

    // ---- Phase A: per-anchor stats (norms, diag sims, margin_cr) ----
    {
        int ar = tid >> 2, q = tid & 3;           // 4 threads per anchor
        int a  = a0 + ar;
        const float4* iv = (const float4*)(img + (size_t)a * ND) + q * 32;
        const float4* tv = (const float4*)(txt + (size_t)a * ND) + q * 32;
        const float4* cv = (const float4*)(cr  + (size_t)a * ND) + q * 32;
        float sii = 0, stt = 0, scc = 0, sit = 0, sic = 0;
        #pragma unroll 8
        for (int i = 0; i < 32; ++i) {
            float4 x = iv[i], y = tv[i], w = cv[i];
            sii += x.x*x.x + x.y*x.y + x.z*x.z + x.w*x.w;
            stt += y.x*y.x + y.y*y.y + y.z*y.z + y.w*y.w;
            scc += w.x*w.x + w.y*w.y + w.z*w.z + w.w*w.w;
            sit += x.x*y.x + x.y*y.y + x.z*y.z + x.w*y.w;
            sic += x.x*w.x + x.y*w.y + x.z*w.z + x.w*w.w;
        }
        // butterfly across the 4 threads of one anchor (same wave: lanes differ in bits 0-1)
        sii += __shfl_xor(sii, 1); sii += __shfl_xor(sii, 2);
        stt += __shfl_xor(stt, 1); stt += __shfl_xor(stt, 2);
        scc += __shfl_xor(scc, 1); scc += __shfl_xor(scc, 2);
        sit += __shfl_xor(sit, 1); sit += __shfl_xor(sit, 2);
        sic += __shfl_xor(sic, 1); sic += __shfl_xor(sic, 2);
        if (q == 0) {
            float rnI = 1.0f / (sqrtf(sii) + 1e-8f);
            float rnT = 1.0f / (sqrtf(stt) + 1e-8f);
            float rnC = 1.0f / (sqrtf(scc) + 1e-8f);
            float ds = sit * rnI * rnT;            // matched sim
            float dc = sic * rnI * rnC;            // matched sim (cr)
            float m  = margin[a];
            float mcr = flag ? (fminf(fabsf(dc) / fabsf(ds), 1.0f) + 1.0f) * m * 0.5f
                             : m * 0.5f;
            aRn[ar]  = (z == 1) ? rnT : (z == 3) ? rnC : rnI;
            aDg[ar]  = (z >= 2) ? dc : ds;
            float mg = (z >= 2) ? mcr : m;
            aMg[ar]  = mg;
            aLab[ar] = labels[a];
            // auto flag + margin < 0.16 -> row contributes 0: pre-resolve as -1.
            resIdx[ar] = (flag && mg < 0.16f) ? -1 : INT_MAX;
        }
        if (tid == 0) blockAcc = 0.0f;
    }
    __syncthreads();

    const int ty4  = (tid >> 4) * 4, tx4 = (tid & 15) * 4;  // 4x4 dot tile per thread
    const int lrow = tid >> 2,  lk4 = (tid & 3) * 4;        // staging role

    for (int jc = 0; jc < NB / 64; ++jc) {
        int j0 = jc * 64;
        float acc[4][4];
        #pragma unroll
        for (int i = 0; i < 4; ++i)
            #pragma unroll
            for (int j = 0; j < 4; ++j) acc[i][j] = 0.0f;
        float bssq = 0.0f;                        // column sum-of-squares partial

        for (int kc = 0; kc < ND; kc += 16) {
            __syncthreads();
            float4 va = *(const float4*)(A + (size_t)(a0 + lrow) * ND + kc + lk4);
            float4 vb = *(const float4*)(B + (size_t)(j0 + lrow) * ND + kc + lk4);
            As[lk4 + 0][lrow] = va.x; As[lk4 + 1][lrow] = va.y;
            As[lk4 + 2][lrow] = va.z; As[lk4 + 3][lrow] = va.w;
            Bs[lk4 + 0][lrow] = vb.x; Bs[lk4 + 1][lrow] = vb.y;
            Bs[lk4 + 2][lrow] = vb.z; Bs[lk4 + 3][lrow] = vb.w;
            bssq += vb.x*vb.x + vb.y*vb.y + vb.z*vb.z + vb.w*vb.w;
            __syncthreads();
            #pragma unroll
            for (int k = 0; k < 16; ++k) {
                float4 av = *(const float4*)&As[k][ty4];
                float4 bv = *(const float4*)&Bs[k][tx4];
                float ar[4] = {av.x, av.y, av.z, av.w};
                float br[4] = {bv.x, bv.y, bv.z, bv.w};
                #pragma unroll
                for (int i = 0; i < 4; ++i)
                    #pragma unroll
                    for (int j = 0; j < 4; ++j)
                        acc[i][j] = fmaf(ar[i], br[j], acc[i][j]);
            }
        }

        // column norms + labels; snapshot resIdx (to detect "newly resolved").
        bssq += __shfl_xor(bssq, 1); bssq += __shfl_xor(bssq, 2);
        __syncthreads();
        if ((tid & 3) == 0) {
            colRn[lrow]  = 1.0f / (sqrtf(bssq) + 1e-8f);
            colLab[lrow] = labels[j0 + lrow];
        }
        if (tid < 64) prevIdx[tid] = resIdx[tid];
        __syncthreads();

        // predicate pass: first valid (min index) via atomicMin
        #pragma unroll
        for (int i = 0; i < 4; ++i) {
            int r = ty4 + i;
            if (prevIdx[r] != INT_MAX) continue;  // already resolved / pre-skipped
            float dg = aDg[r], mgv = aMg[r], rna = aRn[r];
            int la = aLab[r];
            #pragma unroll
            for (int j = 0; j < 4; ++j) {
                int c = tx4 + j;
                if (colLab[c] == la) continue;
                float v  = acc[i][j] * rna * colRn[c];
                float lm = v - dg + mgv;
                if (lm > 0.0f && lm < mgv) atomicMin(&resIdx[r], j0 + c);
            }
        }
        __syncthreads();

        // winner pass: the unique owner thread of the winning column adds lm.
        #pragma unroll
        for (int i = 0; i < 4; ++i) {
            int r = ty4 + i;
            if (prevIdx[r] != INT_MAX) continue;
            int w = resIdx[r];
            if (w == INT_MAX) continue;           // still unresolved
            int c = w - j0 - tx4;
            if (c < 0 || c > 3) continue;         // not my column
            float v  = acc[i][c] * aRn[r] * colRn[tx4 + c];
            float lm = v - aDg[r] + aMg[r];       // == relu(margin - diag + sim_an)
            atomicAdd(&blockAcc, lm);
        }

        // early exit when all rows resolved
        __syncthreads();
        if (tid == 0) cnt = 0;
        __syncthreads();
        if (tid < 64 && resIdx[tid] == INT_MAX) atomicAdd(&cnt, 1);
        __syncthreads();
        int unresolved = cnt;                     // uniform
        __syncthreads();
        if (unresolved == 0) break;
    }

    if (tid == 0 && blockAcc != 0.0f) {
        float scale = (z >= 2) ? betap[0] : 1.0f;
        atomicAdd(out, blockAcc * scale);
    }
}

extern "C" void kernel_launch(void* const* d_in, const int* in_sizes, int n_in,
                              void* d_out, int out_size, void* d_ws, size_t ws_size,
                              hipStream_t stream) {
    const float* img    = (const float*)d_in[0];
    const float* txt    = (const float*)d_in[1];
    const float* cr     = (const float*)d_in[2];
    const int*   labels = (const int*)  d_in[3];
    const int*   flagp  = (const int*)  d_in[4];
    const float* marg   = (const float*)d_in[5];
    const float* betap  = (const float*)d_in[6];
    float* out = (float*)d_out;
    (void)d_ws; (void)ws_size; (void)in_sizes; (void)n_in;

    zero_k<<<dim3((out_size + 255) / 256), dim3(256), 0, stream>>>(out, out_size);
    mine_k<<<dim3(NB / 64, 4), dim3(256), 0, stream>>>(img, txt, cr, labels,
                                                       flagp, marg, betap, out);
}

// Round 3
// 843.186 us; speedup vs baseline: 4.2657x; 4.2657x over previous
//
#include <hip/hip_runtime.h>
#include <climits>

// Problem constants (fixed by the reference): B=8192 rows, D=512 features.
#define NB 8192
#define ND 512

// Zero the scalar output (harness poisons d_out before every timed launch).
__global__ __launch_bounds__(256) void zero_k(float* out, int n) {
    int g = blockIdx.x * 256 + threadIdx.x;
    if (g < n) out[g] = 0.0f;
}

// Straggler scan: u (<=U) unresolved anchors scanned simultaneously, 256
// columns per iteration (one per thread), ascending so per-chunk atomicMin
// preserves FIRST-valid semantics. A-rows are broadcast global loads (all
// lanes same address -> 1 transaction); B-rows stream per-thread from L1/L2.
template <int U>
__device__ void stragScan(const float* __restrict__ A, const float* __restrict__ B,
                          const int* __restrict__ labels, int a0, int u, int scol,
                          const int* sList, int g0,
                          const float* aRn, const float* aDg, const float* aMg,
                          const int* aLab, int* sMin8, int* doneMask,
                          float* blockAcc) {
    const int tid = threadIdx.x;
    float rn_s[U], dg_s[U], mg_s[U];
    int lab_s[U];
    const float4* Av[U];
    #pragma unroll
    for (int s = 0; s < U; ++s) {
        int slot = sList[g0 + (s < u ? s : 0)];
        rn_s[s] = aRn[slot]; dg_s[s] = aDg[slot]; mg_s[s] = aMg[slot];
        lab_s[s] = aLab[slot];
        Av[s] = (const float4*)(A + (size_t)(a0 + slot) * ND);
    }
    if (tid < U) sMin8[tid] = INT_MAX;
    if (tid == 0) *doneMask = 0;
    __syncthreads();

    for (int jb = scol; jb < NB; jb += 256) {
        int j = jb + tid;
        bool jv = (j < NB);
        int mask = *doneMask;                       // stable: barrier'd last iter
        float dot[U];
        #pragma unroll
        for (int s = 0; s < U; ++s) dot[s] = 0.0f;
        float ssq = 0.0f;
        if (jv) {
            const float4* Bv = (const float4*)(B + (size_t)j * ND);
            #pragma unroll 4
            for (int k4 = 0; k4 < ND / 4; ++k4) {
                float4 b = Bv[k4];
                ssq += b.x*b.x + b.y*b.y + b.z*b.z + b.w*b.w;
                #pragma unroll
                for (int s = 0; s < U; ++s) {
                    float4 a = Av[s][k4];
                    dot[s] += a.x*b.x + a.y*b.y + a.z*b.z + a.w*b.w;
                }
            }
        }
        float rnb = 1.0f / (sqrtf(ssq) + 1e-8f);
        int lj = jv ? labels[j] : -1;
        float lmv[U];
        #pragma unroll
        for (int s = 0; s < U; ++s) {
            lmv[s] = dot[s] * rn_s[s] * rnb - dg_s[s] + mg_s[s];
            if (jv && s < u && !((mask >> s) & 1) && lj != lab_s[s] &&
                lmv[s] > 0.0f && lmv[s] < mg_s[s])
                atomicMin(&sMin8[s], j);
        }
        __syncthreads();
        #pragma unroll
        for (int s = 0; s < U; ++s)
            if (jv && s < u && !((mask >> s) & 1) && sMin8[s] == j)
                atomicAdd(blockAcc, lmv[s]);        // unique winner thread
        __syncthreads();
        if (tid == 0) {
            int m2 = 0;
            for (int s = 0; s < u; ++s)
                if (sMin8[s] != INT_MAX) m2 |= (1 << s);
            *doneMask = m2;
        }
        __syncthreads();
        if (*doneMask == (1 << u) - 1) break;       // uniform
    }
}

// Fused semi-hard mining + loss for one pass z per blockIdx.y:
//   z=0: anchors=img rows, scan=txt   (sim rows),    margin
//   z=1: anchors=txt rows, scan=img   (sim.T rows),  margin
//   z=2: anchors=img rows, scan=cr    (sim_cr rows), margin_cr
//   z=3: anchors=cr  rows, scan=img   (sim_cr.T),    margin_cr
__global__ __launch_bounds__(256) void mine_k(const float* __restrict__ img,
                                              const float* __restrict__ txt,
                                              const float* __restrict__ cr,
                                              const int*   __restrict__ labels,
                                              const int*   __restrict__ flagp,
                                              const float* __restrict__ margin,
                                              const float* __restrict__ betap,
                                              float* __restrict__ out) {
    __shared__ __align__(16) float As[16][64];
    __shared__ __align__(16) float Bs[16][64];
    __shared__ float aRn[64], aDg[64], aMg[64];
    __shared__ int   aLab[64];
    __shared__ float colRn[64];
    __shared__ int   colLab[64];
    __shared__ int   resIdx[64], prevIdx[64];
    __shared__ int   cnt;
    __shared__ float blockAcc;
    __shared__ int   sList[64];
    __shared__ int   sCnt;
    __shared__ int   sMin8[8];
    __shared__ int   doneMask;

    const int tid  = threadIdx.x;
    const int z    = blockIdx.y;
    const int a0   = blockIdx.x * 64;
    const int flag = flagp[0];

    const float* A = (z == 1) ? txt : (z == 3) ? cr : img;
    const float* B = (z == 0) ? txt : (z == 2) ? cr : img;

    // ---- Phase A: per-anchor stats (norms, diag sims, margin_cr) ----
    {
        int ar = tid >> 2, q = tid & 3;           // 4 threads per anchor
        int a  = a0 + ar;
        const float4* iv = (const float4*)(img + (size_t)a * ND) + q * 32;
        const float4* tv = (const float4*)(txt + (size_t)a * ND) + q * 32;
        const float4* cv = (const float4*)(cr  + (size_t)a * ND) + q * 32;
        float sii = 0, stt = 0, scc = 0, sit = 0, sic = 0;
        if (z >= 2) {
            #pragma unroll 4
            for (int i = 0; i < 32; ++i) {
                float4 x = iv[i], y = tv[i], w = cv[i];
                sii += x.x*x.x + x.y*x.y + x.z*x.z + x.w*x.w;
                stt += y.x*y.x + y.y*y.y + y.z*y.z + y.w*y.w;
                scc += w.x*w.x + w.y*w.y + w.z*w.z + w.w*w.w;
                sit += x.x*y.x + x.y*y.y + x.z*y.z + x.w*y.w;
                sic += x.x*w.x + x.y*w.y + x.z*w.z + x.w*w.w;
            }
        } else {
            #pragma unroll 4
            for (int i = 0; i < 32; ++i) {
                float4 x = iv[i], y = tv[i];
                sii += x.x*x.x + x.y*x.y + x.z*x.z + x.w*x.w;
                stt += y.x*y.x + y.y*y.y + y.z*y.z + y.w*y.w;
                sit += x.x*y.x + x.y*y.y + x.z*y.z + x.w*y.w;
            }
        }
        sii += __shfl_xor(sii, 1); sii += __shfl_xor(sii, 2);
        stt += __shfl_xor(stt, 1); stt += __shfl_xor(stt, 2);
        sit += __shfl_xor(sit, 1); sit += __shfl_xor(sit, 2);
        if (z >= 2) {
            scc += __shfl_xor(scc, 1); scc += __shfl_xor(scc, 2);
            sic += __shfl_xor(sic, 1); sic += __shfl_xor(sic, 2);
        }
        if (q == 0) {
            float rnI = 1.0f / (sqrtf(sii) + 1e-8f);
            float rnT = 1.0f / (sqrtf(stt) + 1e-8f);
            float ds  = sit * rnI * rnT;          // matched sim
            float m   = margin[a];
            float mg, rna, dgv;
            if (z >= 2) {
                float rnC = 1.0f / (sqrtf(scc) + 1e-8f);
                float dc  = sic * rnI * rnC;      // matched sim (cr)
                float mcr = flag ? (fminf(fabsf(dc) / fabsf(ds), 1.0f) + 1.0f) * m * 0.5f
                                 : m * 0.5f;
                mg = mcr; dgv = dc; rna = (z == 3) ? rnC : rnI;
            } else {
                mg = m; dgv = ds; rna = (z == 1) ? rnT : rnI;
            }
            aRn[ar]  = rna;
            aDg[ar]  = dgv;
            aMg[ar]  = mg;
            aLab[ar] = labels[a];
            // auto flag + margin < 0.16 -> row contributes 0: pre-resolve as -1.
            resIdx[ar] = (flag && mg < 0.16f) ? -1 : INT_MAX;
        }
        if (tid == 0) blockAcc = 0.0f;
    }
    __syncthreads();

    const int ty4  = (tid >> 4) * 4, tx4 = (tid & 15) * 4;  // 4x4 dot tile
    const int lrow = tid >> 2,  lk4 = (tid & 3) * 4;        // staging role

    // ---- Band phase: up to 2 chunks of 64 columns, block-GEMM style ----
    int bandCols = 0, unresolved = 64;
    for (int jc = 0; jc < 2; ++jc) {
        int j0 = jc * 64;
        float acc[4][4];
        #pragma unroll
        for (int i = 0; i < 4; ++i)
            #pragma unroll
            for (int j = 0; j < 4; ++j) acc[i][j] = 0.0f;
        float bssq = 0.0f;

        for (int kc = 0; kc < ND; kc += 16) {
            __syncthreads();
            float4 va = *(const float4*)(A + (size_t)(a0 + lrow) * ND + kc + lk4);
            float4 vb = *(const float4*)(B + (size_t)(j0 + lrow) * ND + kc + lk4);
            As[lk4 + 0][lrow] = va.x; As[lk4 + 1][lrow] = va.y;
            As[lk4 + 2][lrow] = va.z; As[lk4 + 3][lrow] = va.w;
            Bs[lk4 + 0][lrow] = vb.x; Bs[lk4 + 1][lrow] = vb.y;
            Bs[lk4 + 2][lrow] = vb.z; Bs[lk4 + 3][lrow] = vb.w;
            bssq += vb.x*vb.x + vb.y*vb.y + vb.z*vb.z + vb.w*vb.w;
            __syncthreads();
            #pragma unroll
            for (int k = 0; k < 16; ++k) {
                float4 av = *(const float4*)&As[k][ty4];
                float4 bv = *(const float4*)&Bs[k][tx4];
                float ar[4] = {av.x, av.y, av.z, av.w};
                float br[4] = {bv.x, bv.y, bv.z, bv.w};
                #pragma unroll
                for (int i = 0; i < 4; ++i)
                    #pragma unroll
                    for (int j = 0; j < 4; ++j)
                        acc[i][j] = fmaf(ar[i], br[j], acc[i][j]);
            }
        }

        bssq += __shfl_xor(bssq, 1); bssq += __shfl_xor(bssq, 2);
        __syncthreads();
        if ((tid & 3) == 0) {
            colRn[lrow]  = 1.0f / (sqrtf(bssq) + 1e-8f);
            colLab[lrow] = labels[j0 + lrow];
        }
        if (tid < 64) prevIdx[tid] = resIdx[tid];
        __syncthreads();

        #pragma unroll
        for (int i = 0; i < 4; ++i) {
            int r = ty4 + i;
            if (prevIdx[r] != INT_MAX) continue;
            float dg = aDg[r], mgv = aMg[r], rna = aRn[r];
            int la = aLab[r];
            #pragma unroll
            for (int j = 0; j < 4; ++j) {
                int c = tx4 + j;
                if (colLab[c] == la) continue;
                float v  = acc[i][j] * rna * colRn[c];
                float lm = v - dg + mgv;
                if (lm > 0.0f && lm < mgv) atomicMin(&resIdx[r], j0 + c);
            }
        }
        __syncthreads();

        #pragma unroll
        for (int i = 0; i < 4; ++i) {
            int r = ty4 + i;
            if (prevIdx[r] != INT_MAX) continue;
            int w = resIdx[r];
            if (w == INT_MAX) continue;
            int c = w - j0 - tx4;
            if (c < 0 || c > 3) continue;         // unique owner thread
            float v  = acc[i][c] * aRn[r] * colRn[tx4 + c];
            float lm = v - aDg[r] + aMg[r];
            atomicAdd(&blockAcc, lm);
        }

        __syncthreads();
        if (tid == 0) cnt = 0;
        __syncthreads();
        if (tid < 64 && resIdx[tid] == INT_MAX) atomicAdd(&cnt, 1);
        __syncthreads();
        unresolved = cnt;                          // uniform
        bandCols = j0 + 64;
        __syncthreads();
        if (unresolved <= 8) break;                // few left: straggler mode
    }

    // ---- Straggler phase ----
    if (unresolved > 0) {
        if (tid == 0) sCnt = 0;
        __syncthreads();
        if (tid < 64 && resIdx[tid] == INT_MAX) {
            int pos = atomicAdd(&sCnt, 1);
            sList[pos] = tid;
        }
        __syncthreads();
        int total = sCnt;                          // uniform
        for (int g0 = 0; g0 < total; g0 += 8) {
            int u = min(8, total - g0);
            if (u == 1)
                stragScan<1>(A, B, labels, a0, u, bandCols, sList, g0,
                             aRn, aDg, aMg, aLab, sMin8, &doneMask, &blockAcc);
            else if (u == 2)
                stragScan<2>(A, B, labels, a0, u, bandCols, sList, g0,
                             aRn, aDg, aMg, aLab, sMin8, &doneMask, &blockAcc);
            else if (u <= 4)
                stragScan<4>(A, B, labels, a0, u, bandCols, sList, g0,
                             aRn, aDg, aMg, aLab, sMin8, &doneMask, &blockAcc);
            else
                stragScan<8>(A, B, labels, a0, u, bandCols, sList, g0,
                             aRn, aDg, aMg, aLab, sMin8, &doneMask, &blockAcc);
            __syncthreads();
        }
    }

    if (tid == 0 && blockAcc != 0.0f) {
        float scale = (z >= 2) ? betap[0] : 1.0f;
        atomicAdd(out, blockAcc * scale);
    }
}

extern "C" void kernel_launch(void* const* d_in, const int* in_sizes, int n_in,
                              void* d_out, int out_size, void* d_ws, size_t ws_size,
                              hipStream_t stream) {
    const float* img    = (const float*)d_in[0];
    const float* txt    = (const float*)d_in[1];
    const float* cr     = (const float*)d_in[2];
    const int*   labels = (const int*)  d_in[3];
    const int*   flagp  = (const int*)  d_in[4];
    const float* marg   = (const float*)d_in[5];
    const float* betap  = (const float*)d_in[6];
    float* out = (float*)d_out;
    (void)d_ws; (void)ws_size; (void)in_sizes; (void)n_in;

    zero_k<<<dim3((out_size + 255) / 256), dim3(256), 0, stream>>>(out, out_size);
    mine_k<<<dim3(NB / 64, 4), dim3(256), 0, stream>>>(img, txt, cr, labels,
                                                       flagp, marg, betap, out);
}